// Round 2
// baseline (173.020 us; speedup 1.0000x reference)
//
#include <hip/hip_runtime.h>
#include <hip/hip_bf16.h>

typedef __attribute__((ext_vector_type(8))) short bf16x8;
typedef __attribute__((ext_vector_type(4))) float f32x4;

#define N_IN  128
#define N_HID 64
#define LDS_PAD 8      // bf16 elements of pad per row
#define TPB 256
#define WAVES_PER_BLOCK 4
#define GRID_BLOCKS 768   // 3 blocks/CU x 256 CU -> fully-resident persistent grid

// 4-op round-to-nearest-even f32->bf16. Inputs are finite (Gaussian data),
// so skip the NaN branch that __float2bfloat16 carries.
static __device__ inline short f2bf(float f) {
    unsigned u = __float_as_uint(f);
    u += 0x7fffu + ((u >> 16) & 1u);
    return (short)(u >> 16);
}

__global__ __launch_bounds__(TPB, 3)
void atomwise_mfma_kernel(const float* __restrict__ x,
                          const float* __restrict__ W1,
                          const float* __restrict__ b1,
                          const float* __restrict__ W2,
                          const float* __restrict__ b2,
                          const int*   __restrict__ idx_m,
                          float*       __restrict__ out,
                          int n_atoms)
{
    __shared__ short w1t[N_HID][N_IN + LDS_PAD];   // W1^T in bf16

    const int tid = threadIdx.x;

    // ---- one-time: stage W1^T (bf16) into LDS. W1 is [128][64] row-major ----
    for (int e = tid; e < N_IN * N_HID; e += TPB) {
        int k = e >> 6;     // 0..127
        int n = e & 63;     // 0..63
        w1t[n][k] = f2bf(W1[e]);
    }
    __syncthreads();

    const int lane = tid & 63;
    const int wv   = tid >> 6;
    const int l15  = lane & 15;
    const int g    = lane >> 4;     // 0..3 (k-group; also selects atoms g*4..g*4+3)

    // ---- hoist full B operand (W1^T fragments) into registers ----
    bf16x8 bfrag[4][4];             // [kt][nt]
    #pragma unroll
    for (int kt = 0; kt < 4; ++kt)
        #pragma unroll
        for (int nt = 0; nt < 4; ++nt) {
            const short* p = &w1t[nt * 16 + l15][kt * 32 + g * 8];
            bfrag[kt][nt] = *reinterpret_cast<const bf16x8*>(p);
        }

    // per-lane channel constants: channel = nt*16 + l15
    float bb[4], w2v[4];
    #pragma unroll
    for (int nt = 0; nt < 4; ++nt) {
        bb[nt]  = b1[nt * 16 + l15];
        w2v[nt] = W2[nt * 16 + l15];
    }
    const float b2v = b2[0];

    const int n_tiles = (n_atoms + 15) >> 4;
    const int n_waves = gridDim.x * WAVES_PER_BLOCK;
    int tile = blockIdx.x * WAVES_PER_BLOCK + wv;
    if (tile >= n_tiles) return;

    // ---- prologue: issue loads for first tile ----
    f32x4 xf[8];
    int mv;     // idx_m for atom (tile*16 + l15), clamped
    {
        int row  = tile * 16 + l15;
        int rowc = row < n_atoms ? row : (n_atoms - 1);
        const float* xp = x + (size_t)rowc * N_IN + g * 8;
        #pragma unroll
        for (int kt = 0; kt < 4; ++kt) {
            xf[2 * kt]     = *reinterpret_cast<const f32x4*>(xp + kt * 32);
            xf[2 * kt + 1] = *reinterpret_cast<const f32x4*>(xp + kt * 32 + 4);
        }
        mv = idx_m[rowc];
    }

    while (true) {
        // ---- convert current tile to bf16 A-fragments (waits vmcnt on its loads) ----
        bf16x8 a[4];
        #pragma unroll
        for (int kt = 0; kt < 4; ++kt) {
            f32x4 lo = xf[2 * kt];
            f32x4 hi = xf[2 * kt + 1];
            bf16x8 t;
            t[0] = f2bf(lo[0]); t[1] = f2bf(lo[1]);
            t[2] = f2bf(lo[2]); t[3] = f2bf(lo[3]);
            t[4] = f2bf(hi[0]); t[5] = f2bf(hi[1]);
            t[6] = f2bf(hi[2]); t[7] = f2bf(hi[3]);
            a[kt] = t;
        }

        // ---- prefetch next tile's x + idx into the (now free) buffers ----
        const int  ntile     = tile + n_waves;
        const bool have_next = ntile < n_tiles;
        int nmv = 0;
        if (have_next) {            // wave-uniform branch; loop backedge only from here
            int row  = ntile * 16 + l15;
            int rowc = row < n_atoms ? row : (n_atoms - 1);
            const float* xp = x + (size_t)rowc * N_IN + g * 8;
            #pragma unroll
            for (int kt = 0; kt < 4; ++kt) {
                xf[2 * kt]     = *reinterpret_cast<const f32x4*>(xp + kt * 32);
                xf[2 * kt + 1] = *reinterpret_cast<const f32x4*>(xp + kt * 32 + 4);
            }
            nmv = idx_m[rowc];
        }

        // ---- MFMA: 16 atoms x 64 hid over K=128 ----
        f32x4 acc[4] = {};          // [nt]; rows g*4+j, col l15
        #pragma unroll
        for (int kt = 0; kt < 4; ++kt)
            #pragma unroll
            for (int nt = 0; nt < 4; ++nt)
                acc[nt] = __builtin_amdgcn_mfma_f32_16x16x32_bf16(
                              a[kt], bfrag[kt][nt], acc[nt], 0, 0, 0);

        // ---- epilogue: bias + silu + dot(W2) ----
        float p[4];
        #pragma unroll
        for (int j = 0; j < 4; ++j) {
            float s = 0.f;
            #pragma unroll
            for (int nt = 0; nt < 4; ++nt) {
                float z = acc[nt][j] + bb[nt];
                float h = z / (1.f + __expf(-z));   // silu
                s += h * w2v[nt];
            }
            p[j] = s;
        }

        // ---- allreduce over the 16 lanes sharing g (sums channels over l15) ----
        // After this, all lanes of group g hold the full sum for atoms g*4+j in p[j].
        #pragma unroll
        for (int m = 1; m < 16; m <<= 1) {
            #pragma unroll
            for (int j = 0; j < 4; ++j)
                p[j] += __shfl_xor(p[j], m, 64);
        }

        // ---- redistribute: lane k (0..15) gets atom k's sum; single atomic ----
        // atom k = (k>>2)*4 + (k&3); its sum lives in p[k&3] on any lane of group k>>2.
        {
            const int src = (lane >> 2) << 4;       // lane (k>>2)*16
            float t0 = __shfl(p[0], src, 64);
            float t1 = __shfl(p[1], src, 64);
            float t2 = __shfl(p[2], src, 64);
            float t3 = __shfl(p[3], src, 64);
            int jj = lane & 3;
            float v = (jj == 0) ? t0 : (jj == 1) ? t1 : (jj == 2) ? t2 : t3;
            // lanes 0..15: mv already holds idx_m of atom tile*16+lane
            int atom = tile * 16 + lane;
            if (lane < 16 && atom < n_atoms)        // 1-instr masked body, no skip branch
                atomicAdd(&out[mv], v + b2v);
        }

        if (!have_next) break;
        tile = ntile;
        mv   = nmv;
    }
}

extern "C" void kernel_launch(void* const* d_in, const int* in_sizes, int n_in,
                              void* d_out, int out_size, void* d_ws, size_t ws_size,
                              hipStream_t stream) {
    const float* x   = (const float*)d_in[0];
    const float* W1  = (const float*)d_in[1];
    const float* b1  = (const float*)d_in[2];
    const float* W2  = (const float*)d_in[3];
    const float* b2  = (const float*)d_in[4];
    const int*   idx = (const int*)d_in[5];
    // d_in[6] = num_segments (scalar) — equals out_size

    const int n_atoms = in_sizes[0] / N_IN;
    float* out = (float*)d_out;

    hipMemsetAsync(d_out, 0, (size_t)out_size * sizeof(float), stream);

    atomwise_mfma_kernel<<<GRID_BLOCKS, TPB, 0, stream>>>(
        x, W1, b1, W2, b2, idx, out, n_atoms);
}

// Round 3
// 142.209 us; speedup vs baseline: 1.2167x; 1.2167x over previous
//
#include <hip/hip_runtime.h>
#include <hip/hip_bf16.h>

typedef __attribute__((ext_vector_type(8))) short bf16x8;
typedef __attribute__((ext_vector_type(4))) float f32x4;

#define N_IN  128
#define N_HID 64
#define LDS_PAD 8      // bf16 elements of pad per row
#define TPB 256
#define WAVES_PER_BLOCK 4

// 4-op round-to-nearest-even f32->bf16. Inputs are finite (Gaussian data),
// so skip the NaN branch that __float2bfloat16 carries.
static __device__ inline short f2bf(float f) {
    unsigned u = __float_as_uint(f);
    u += 0x7fffu + ((u >> 16) & 1u);
    return (short)(u >> 16);
}

__global__ __launch_bounds__(TPB, 3)
void atomwise_mfma_kernel(const float* __restrict__ x,
                          const float* __restrict__ W1,
                          const float* __restrict__ b1,
                          const float* __restrict__ W2,
                          const float* __restrict__ b2,
                          const int*   __restrict__ idx_m,
                          float*       __restrict__ out,
                          int n_atoms)
{
    __shared__ short w1t[N_HID][N_IN + LDS_PAD];   // W1^T in bf16

    const int tid = threadIdx.x;

    // ---- one-time: stage W1^T (bf16) into LDS. W1 is [128][64] row-major ----
    for (int e = tid; e < N_IN * N_HID; e += TPB) {
        int k = e >> 6;     // 0..127
        int n = e & 63;     // 0..63
        w1t[n][k] = f2bf(W1[e]);
    }
    __syncthreads();

    const int lane = tid & 63;
    const int wv   = tid >> 6;
    const int l15  = lane & 15;
    const int g    = lane >> 4;     // 0..3 (k-group; also selects atoms g*4..g*4+3)

    // ---- hoist full B operand (W1^T fragments) into registers ----
    bf16x8 bfrag[4][4];             // [kt][nt]
    #pragma unroll
    for (int kt = 0; kt < 4; ++kt)
        #pragma unroll
        for (int nt = 0; nt < 4; ++nt) {
            const short* p = &w1t[nt * 16 + l15][kt * 32 + g * 8];
            bfrag[kt][nt] = *reinterpret_cast<const bf16x8*>(p);
        }

    // per-lane channel constants: channel = nt*16 + l15
    float bb[4], w2v[4];
    #pragma unroll
    for (int nt = 0; nt < 4; ++nt) {
        bb[nt]  = b1[nt * 16 + l15];
        w2v[nt] = W2[nt * 16 + l15];
    }
    const float b2v = b2[0];

    const int n_tiles = (n_atoms + 15) >> 4;
    const int n_waves = gridDim.x * WAVES_PER_BLOCK;
    int tile = blockIdx.x * WAVES_PER_BLOCK + wv;
    if (tile >= n_tiles) return;

    // ---- prologue: issue loads for first tile ----
    f32x4 xf[8];
    int mv;     // idx_m for atom (tile*16 + l15), clamped
    {
        int row  = tile * 16 + l15;
        int rowc = row < n_atoms ? row : (n_atoms - 1);
        const float* xp = x + (size_t)rowc * N_IN + g * 8;
        #pragma unroll
        for (int kt = 0; kt < 4; ++kt) {
            xf[2 * kt]     = *reinterpret_cast<const f32x4*>(xp + kt * 32);
            xf[2 * kt + 1] = *reinterpret_cast<const f32x4*>(xp + kt * 32 + 4);
        }
        mv = idx_m[rowc];
    }

    while (true) {
        // ---- convert current tile to bf16 A-fragments (waits vmcnt on its loads) ----
        bf16x8 a[4];
        #pragma unroll
        for (int kt = 0; kt < 4; ++kt) {
            f32x4 lo = xf[2 * kt];
            f32x4 hi = xf[2 * kt + 1];
            bf16x8 t;
            t[0] = f2bf(lo[0]); t[1] = f2bf(lo[1]);
            t[2] = f2bf(lo[2]); t[3] = f2bf(lo[3]);
            t[4] = f2bf(hi[0]); t[5] = f2bf(hi[1]);
            t[6] = f2bf(hi[2]); t[7] = f2bf(hi[3]);
            a[kt] = t;
        }

        // ---- prefetch next tile's x + idx into the (now free) buffers ----
        const int  ntile     = tile + n_waves;
        const bool have_next = ntile < n_tiles;
        int nmv = 0;
        if (have_next) {            // wave-uniform branch; loop backedge only from here
            int row  = ntile * 16 + l15;
            int rowc = row < n_atoms ? row : (n_atoms - 1);
            const float* xp = x + (size_t)rowc * N_IN + g * 8;
            #pragma unroll
            for (int kt = 0; kt < 4; ++kt) {
                xf[2 * kt]     = *reinterpret_cast<const f32x4*>(xp + kt * 32);
                xf[2 * kt + 1] = *reinterpret_cast<const f32x4*>(xp + kt * 32 + 4);
            }
            nmv = idx_m[rowc];
        }

        // ---- MFMA: 16 atoms x 64 hid over K=128 ----
        f32x4 acc[4] = {};          // [nt]; rows g*4+j, col l15
        #pragma unroll
        for (int kt = 0; kt < 4; ++kt)
            #pragma unroll
            for (int nt = 0; nt < 4; ++nt)
                acc[nt] = __builtin_amdgcn_mfma_f32_16x16x32_bf16(
                              a[kt], bfrag[kt][nt], acc[nt], 0, 0, 0);

        // ---- epilogue: bias + silu + dot(W2) ----
        float p[4];
        #pragma unroll
        for (int j = 0; j < 4; ++j) {
            float s = 0.f;
            #pragma unroll
            for (int nt = 0; nt < 4; ++nt) {
                float z = acc[nt][j] + bb[nt];
                float h = z / (1.f + __expf(-z));   // silu
                s += h * w2v[nt];
            }
            p[j] = s;
        }

        // ---- allreduce over the 16 lanes sharing g (sums channels over l15) ----
        // After this, all lanes of group g hold the full sum for atoms g*4+j in p[j].
        #pragma unroll
        for (int m = 1; m < 16; m <<= 1) {
            #pragma unroll
            for (int j = 0; j < 4; ++j)
                p[j] += __shfl_xor(p[j], m, 64);
        }

        // ---- redistribute: lane k (0..15) gets atom k's full sum ----
        // atom k: g = k>>2, j = k&3; its sum lives in p[k&3] on lane (k>>2)*16.
        float v;
        {
            const int src = (lane >> 2) << 4;       // lane (k>>2)*16
            float t0 = __shfl(p[0], src, 64);
            float t1 = __shfl(p[1], src, 64);
            float t2 = __shfl(p[2], src, 64);
            float t3 = __shfl(p[3], src, 64);
            int jj = lane & 3;
            v = (jj == 0) ? t0 : (jj == 1) ? t1 : (jj == 2) ? t2 : t3;
        }

        // ---- segmented sum by molecule id over the 16 atom lanes (ids sorted
        //      -> contiguous runs), then ONE atomic from each run's last lane.
        //      Exactly one atomic instruction per tile, no same-address lanes. ----
        {
            int atom = tile * 16 + l15;             // lanes>=16 mirror lane&15
            float s = (atom < n_atoms) ? v + b2v : 0.f;   // fold b2 per valid atom
            #pragma unroll
            for (int d = 1; d < 16; d <<= 1) {
                float us = __shfl_up(s,  d, 16);
                int   um = __shfl_up(mv, d, 16);
                s += (l15 >= d && um == mv) ? us : 0.f;
            }
            int  nm   = __shfl_down(mv, 1, 16);
            bool last = (l15 == 15) || (nm != mv);
            if (lane < 16 && last)
                atomicAdd(&out[mv], s);
        }

        if (!have_next) break;
        tile = ntile;
        mv   = nmv;
    }
}

extern "C" void kernel_launch(void* const* d_in, const int* in_sizes, int n_in,
                              void* d_out, int out_size, void* d_ws, size_t ws_size,
                              hipStream_t stream) {
    const float* x   = (const float*)d_in[0];
    const float* W1  = (const float*)d_in[1];
    const float* b1  = (const float*)d_in[2];
    const float* W2  = (const float*)d_in[3];
    const float* b2  = (const float*)d_in[4];
    const int*   idx = (const int*)d_in[5];
    // d_in[6] = num_segments (scalar) — equals out_size

    const int n_atoms = in_sizes[0] / N_IN;
    float* out = (float*)d_out;

    hipMemsetAsync(d_out, 0, (size_t)out_size * sizeof(float), stream);

    const int blocks = 2048;
    atomwise_mfma_kernel<<<blocks, TPB, 0, stream>>>(
        x, W1, b1, W2, b2, idx, out, n_atoms);
}